// Round 1
// baseline (2004.536 us; speedup 1.0000x reference)
//
#include <hip/hip_runtime.h>
#include <hip/hip_bf16.h>
#include <cmath>

typedef __bf16 bf16_t;
typedef bf16_t bf16x8 __attribute__((ext_vector_type(8)));
typedef float f32x4 __attribute__((ext_vector_type(4)));

#define B_ 32
#define T_ 64
#define D_ 512
#define H_ 1024
#define V_ 20000
#define KTOT 1536   // H + D fused K

// ---------------- casts ----------------
__global__ __launch_bounds__(256) void k_cast(const float* __restrict__ s,
                                              bf16_t* __restrict__ d, int n8) {
    int i = blockIdx.x * 256 + threadIdx.x;
    if (i >= n8) return;
    const f32x4* sv = (const f32x4*)s + (size_t)i * 2;
    f32x4 v0 = sv[0], v1 = sv[1];
    bf16x8 o;
    o[0] = (bf16_t)v0[0]; o[1] = (bf16_t)v0[1]; o[2] = (bf16_t)v0[2]; o[3] = (bf16_t)v0[3];
    o[4] = (bf16_t)v1[0]; o[5] = (bf16_t)v1[1]; o[6] = (bf16_t)v1[2]; o[7] = (bf16_t)v1[3];
    *((bf16x8*)d + i) = o;
}

// src contiguous [rows][cols8*8] -> dst rows with stride dstride, col offset doff
__global__ __launch_bounds__(256) void k_cast_strided(const float* __restrict__ s,
                                                      bf16_t* __restrict__ d, int n,
                                                      int c8shift, int dstride, int doff) {
    int i = blockIdx.x * 256 + threadIdx.x;
    if (i >= n) return;
    int r = i >> c8shift;
    int c = i - (r << c8shift);
    const f32x4* sv = (const f32x4*)(s + ((size_t)i << 3));
    f32x4 v0 = sv[0], v1 = sv[1];
    bf16x8 o;
    o[0] = (bf16_t)v0[0]; o[1] = (bf16_t)v0[1]; o[2] = (bf16_t)v0[2]; o[3] = (bf16_t)v0[3];
    o[4] = (bf16_t)v1[0]; o[5] = (bf16_t)v1[1]; o[6] = (bf16_t)v1[2]; o[7] = (bf16_t)v1[3];
    *(bf16x8*)(d + (size_t)r * dstride + doff + (c << 3)) = o;
}

// ---------------- fused LSTM step ----------------
// grid 64 blocks (16 H-cols each), 512 threads = 8 waves.
// wave w: gate (w&3), K-half (w>>2). K = 1536 = h(1024) ++ x(512).
// MFMA 16x16x32: A row = lane&15 (batch), k = (lane>>4)*8+j ; C: col = lane&15, row=(lane>>4)*4+reg
__global__ __launch_bounds__(512) void k_step(const bf16_t* __restrict__ hbase, int hstride,
                                              const bf16_t* __restrict__ xbase,
                                              const bf16_t* __restrict__ Wbf,
                                              const float* __restrict__ bih,
                                              const float* __restrict__ bhh,
                                              float* __restrict__ cbuf,
                                              bf16_t* __restrict__ hout) {
    __shared__ float lds[8][32][16];
    int tid = threadIdx.x;
    int w = tid >> 6, l = tid & 63;
    int g = w & 3, kh = w >> 2;
    int cg = blockIdx.x;
    int lr = l & 15, lk = (l >> 4) << 3;

    const bf16_t* Wrow = Wbf + (size_t)((g << 10) + (cg << 4) + lr) * KTOT + lk;
    const bf16_t* h0p = hbase + (size_t)lr * hstride + lk;
    const bf16_t* h1p = hbase + (size_t)(lr + 16) * hstride + lk;
    const bf16_t* x0p = xbase + (size_t)lr * (T_ * D_) + lk;
    const bf16_t* x1p = xbase + (size_t)(lr + 16) * (T_ * D_) + lk;

    f32x4 acc0 = {}, acc1 = {};
#pragma unroll
    for (int kt = 0; kt < 24; ++kt) {
        int k = kh * 768 + kt * 32;   // wave-uniform; 1024 boundary aligns to 32
        bf16x8 a0, a1;
        if (k < 1024) {
            a0 = *(const bf16x8*)(h0p + k);
            a1 = *(const bf16x8*)(h1p + k);
        } else {
            a0 = *(const bf16x8*)(x0p + (k - 1024));
            a1 = *(const bf16x8*)(x1p + (k - 1024));
        }
        bf16x8 bb = *(const bf16x8*)(Wrow + k);
        acc0 = __builtin_amdgcn_mfma_f32_16x16x32_bf16(a0, bb, acc0, 0, 0, 0);
        acc1 = __builtin_amdgcn_mfma_f32_16x16x32_bf16(a1, bb, acc1, 0, 0, 0);
    }

    int crow = (l >> 4) << 2;
#pragma unroll
    for (int r = 0; r < 4; ++r) {
        lds[w][crow + r][lr]      = acc0[r];
        lds[w][crow + r + 16][lr] = acc1[r];
    }
    __syncthreads();

    // cell update: 512 threads, one (batch,col) each
    int b = tid >> 4, n = tid & 15;
    int col = (cg << 4) + n;
    float xi = lds[0][b][n] + lds[4][b][n] + bih[col] + bhh[col];
    float xf = lds[1][b][n] + lds[5][b][n] + bih[H_ + col] + bhh[H_ + col];
    float xg = lds[2][b][n] + lds[6][b][n] + bih[2 * H_ + col] + bhh[2 * H_ + col];
    float xo = lds[3][b][n] + lds[7][b][n] + bih[3 * H_ + col] + bhh[3 * H_ + col];
    float ig = 1.f / (1.f + __expf(-xi));
    float fg = 1.f / (1.f + __expf(-xf));
    float gg = tanhf(xg);
    float og = 1.f / (1.f + __expf(-xo));
    float c  = cbuf[(b << 10) + col];
    float cn = fg * c + ig * gg;
    cbuf[(b << 10) + col] = cn;
    float hn = og * tanhf(cn);
    hout[(size_t)b * (T_ * H_) + col] = (bf16_t)hn;   // row m = b*64 + t
}

// ---------------- logits GEMM (bf16 MFMA, direct-from-global) ----------------
// block tile 128x128, 8 waves (2M x 4N), wave tile 64x32
__global__ __launch_bounds__(512) void k_gemm(const bf16_t* __restrict__ A,
                                              const bf16_t* __restrict__ Bt,
                                              const float* __restrict__ blin,
                                              float* __restrict__ out, int nbn) {
    int bid = blockIdx.x;
    int bn = bid % nbn, bm = bid / nbn;
    int tid = threadIdx.x, w = tid >> 6, l = tid & 63;
    int wm = w >> 2, wn = w & 3;
    int r0 = (bm << 7) + (wm << 6);
    int c0 = (bn << 7) + (wn << 5);
    int lr = l & 15, lk = (l >> 4) << 3;

    const bf16_t* ap[4];
#pragma unroll
    for (int mt = 0; mt < 4; ++mt)
        ap[mt] = A + (size_t)(r0 + mt * 16 + lr) * H_ + lk;
    const bf16_t* bp[2];
    int cols[2];
#pragma unroll
    for (int nt = 0; nt < 2; ++nt) {
        int v = c0 + nt * 16 + lr;
        cols[nt] = v;
        int vc = v < V_ ? v : V_ - 1;
        bp[nt] = Bt + (size_t)vc * H_ + lk;
    }

    f32x4 acc[4][2] = {};
#pragma unroll 4
    for (int kt = 0; kt < 32; ++kt) {
        bf16x8 bv0 = *(const bf16x8*)(bp[0] + kt * 32);
        bf16x8 bv1 = *(const bf16x8*)(bp[1] + kt * 32);
#pragma unroll
        for (int mt = 0; mt < 4; ++mt) {
            bf16x8 av = *(const bf16x8*)(ap[mt] + kt * 32);
            acc[mt][0] = __builtin_amdgcn_mfma_f32_16x16x32_bf16(av, bv0, acc[mt][0], 0, 0, 0);
            acc[mt][1] = __builtin_amdgcn_mfma_f32_16x16x32_bf16(av, bv1, acc[mt][1], 0, 0, 0);
        }
    }

    int crow = (l >> 4) << 2;
#pragma unroll
    for (int nt = 0; nt < 2; ++nt) {
        int col = cols[nt];
        if (col >= V_) continue;
        float bl = blin[col];
#pragma unroll
        for (int mt = 0; mt < 4; ++mt) {
            int row = r0 + mt * 16 + crow;
#pragma unroll
            for (int r = 0; r < 4; ++r)
                out[(size_t)(row + r) * V_ + col] = acc[mt][nt][r] + bl;
        }
    }
}

// ---------------- log-softmax ----------------
__global__ __launch_bounds__(256) void k_lse(const float* __restrict__ out,
                                             float* __restrict__ lse) {
    int m = blockIdx.x, tid = threadIdx.x;
    const f32x4* row = (const f32x4*)(out + (size_t)m * V_);
    float mx = -3.4e38f, s = 0.f;
    for (int i = tid; i < V_ / 4; i += 256) {
        f32x4 v = row[i];
#pragma unroll
        for (int j = 0; j < 4; ++j) {
            float x = v[j];
            if (x > mx) { s = s * __expf(mx - x) + 1.f; mx = x; }
            else        { s += __expf(x - mx); }
        }
    }
#pragma unroll
    for (int off = 1; off < 64; off <<= 1) {
        float m2 = __shfl_xor(mx, off);
        float s2 = __shfl_xor(s, off);
        float nm = fmaxf(mx, m2);
        s = s * __expf(mx - nm) + s2 * __expf(m2 - nm);
        mx = nm;
    }
    __shared__ float lm[4], ls[4];
    int w = tid >> 6, l = tid & 63;
    if (l == 0) { lm[w] = mx; ls[w] = s; }
    __syncthreads();
    if (tid == 0) {
        float M = lm[0], S = ls[0];
        for (int i = 1; i < 4; ++i) {
            float nm = fmaxf(M, lm[i]);
            S = S * __expf(M - nm) + ls[i] * __expf(lm[i] - nm);
            M = nm;
        }
        lse[m] = M + __logf(S);
    }
}

__global__ __launch_bounds__(256) void k_sub(float* __restrict__ out,
                                             const float* __restrict__ lse) {
    int m = blockIdx.x, tid = threadIdx.x;
    float L = lse[m];
    f32x4* row = (f32x4*)(out + (size_t)m * V_);
    for (int i = tid; i < V_ / 4; i += 256) {
        f32x4 v = row[i];
        v[0] -= L; v[1] -= L; v[2] -= L; v[3] -= L;
        row[i] = v;
    }
}

// ---------------- launch ----------------
extern "C" void kernel_launch(void* const* d_in, const int* in_sizes, int n_in,
                              void* d_out, int out_size, void* d_ws, size_t ws_size,
                              hipStream_t stream) {
    const float* isequence = (const float*)d_in[0];  // [B][T][D]
    const float* hidden    = (const float*)d_in[1];  // [B][H]
    const float* W_ih      = (const float*)d_in[2];  // [4H][D]
    const float* W_hh      = (const float*)d_in[3];  // [4H][H]
    const float* b_ih      = (const float*)d_in[4];
    const float* b_hh      = (const float*)d_in[5];
    const float* W_lin     = (const float*)d_in[6];  // [V][H]
    const float* b_lin     = (const float*)d_in[7];
    float* out = (float*)d_out;

    auto pad = [](size_t x) { return (x + 255) & ~(size_t)255; };
    const size_t SZ_WBF  = (size_t)4 * H_ * KTOT * 2;
    const size_t SZ_XBF  = (size_t)B_ * T_ * D_ * 2;
    const size_t SZ_H0   = (size_t)B_ * H_ * 2;
    const size_t SZ_C    = (size_t)B_ * H_ * 4;
    const size_t SZ_HALL = (size_t)B_ * T_ * H_ * 2;
    const size_t SZ_WLIN = (size_t)V_ * H_ * 2;
    const size_t SZ_LSE  = (size_t)B_ * T_ * 4;
    size_t needB = pad(SZ_HALL) + pad(SZ_WLIN) + pad(SZ_LSE);
    size_t needA = pad(SZ_WBF) + pad(SZ_XBF) + pad(SZ_H0) + pad(SZ_C);

    char* wsb = (char*)d_ws;
    // group B (live through phase 3) always in ws; group A (dead before phase 3)
    // falls back into d_out if ws is small — d_out is fully rewritten by k_gemm.
    char* arenaA = (ws_size >= needA + needB) ? (wsb + needB) : (char*)d_out;

    bf16_t* h_all   = (bf16_t*)wsb;                                   // [2048][H], row m=b*64+t
    bf16_t* wlin_bf = (bf16_t*)(wsb + pad(SZ_HALL));
    float*  lse     = (float*)(wsb + pad(SZ_HALL) + pad(SZ_WLIN));
    bf16_t* W_bf    = (bf16_t*)arenaA;                                // [4H][KTOT] = [Whh | Wih]
    bf16_t* x_bf    = (bf16_t*)(arenaA + pad(SZ_WBF));
    bf16_t* h0_bf   = (bf16_t*)(arenaA + pad(SZ_WBF) + pad(SZ_XBF));
    float*  cbuf    = (float*)(arenaA + pad(SZ_WBF) + pad(SZ_XBF) + pad(SZ_H0));

    // casts
    k_cast<<<(B_ * T_ * D_ / 8 + 255) / 256, 256, 0, stream>>>(isequence, x_bf, B_ * T_ * D_ / 8);
    k_cast<<<(V_ * H_ / 8 + 255) / 256, 256, 0, stream>>>(W_lin, wlin_bf, V_ * H_ / 8);
    k_cast<<<(B_ * H_ / 8 + 255) / 256, 256, 0, stream>>>(hidden, h0_bf, B_ * H_ / 8);
    k_cast_strided<<<4096 * 128 / 256, 256, 0, stream>>>(W_hh, W_bf, 4096 * 128, 7, KTOT, 0);
    k_cast_strided<<<4096 * 64 / 256, 256, 0, stream>>>(W_ih, W_bf, 4096 * 64, 6, KTOT, 1024);
    hipMemsetAsync(cbuf, 0, SZ_C, stream);

    // recurrence: 64 fused step kernels
    for (int t = 0; t < T_; ++t) {
        const bf16_t* hbase = (t == 0) ? h0_bf : (h_all + (size_t)(t - 1) * H_);
        int hstride = (t == 0) ? H_ : T_ * H_;
        k_step<<<64, 512, 0, stream>>>(hbase, hstride, x_bf + (size_t)t * D_,
                                       W_bf, b_ih, b_hh, cbuf,
                                       h_all + (size_t)t * H_);
    }

    // logits GEMM + log-softmax
    int nbn = (V_ + 127) / 128;  // 157
    k_gemm<<<nbn * (B_ * T_ / 128), 512, 0, stream>>>(h_all, wlin_bf, b_lin, out, nbn);
    k_lse<<<B_ * T_, 256, 0, stream>>>(out, lse);
    k_sub<<<B_ * T_, 256, 0, stream>>>(out, lse);
}